// Round 16
// baseline (138.153 us; speedup 1.0000x reference)
//
#include <hip/hip_runtime.h>

typedef unsigned int u32;
typedef unsigned short u16;
typedef __attribute__((ext_vector_type(8))) short bf16x8;
typedef __attribute__((ext_vector_type(8))) u16 u16x8;
typedef __attribute__((ext_vector_type(4))) u16 u16x4;
typedef __attribute__((ext_vector_type(4))) float f32x4;
typedef __attribute__((ext_vector_type(2))) u32 u32x2;

#define AS1 __attribute__((address_space(1)))
#define AS3 __attribute__((address_space(3)))

__device__ __forceinline__ void gload_lds16(const void* g, void* l) {
  __builtin_amdgcn_global_load_lds((const AS1 u32*)g, (AS3 u32*)l, 16, 0, 0);
}

__device__ __forceinline__ u16 f2bf(float f) {
  union { float f; u32 u; } x; x.f = f;
  u32 u = x.u;
  return (u16)((u + 0x7fffu + ((u >> 16) & 1u)) >> 16);
}

__device__ __forceinline__ float bf2f(u16 v) {
  union { u32 u; float f; } x; x.u = (u32)v << 16; return x.f;
}

__device__ __forceinline__ u32 cvt_pk_bf16(float lo, float hi) {
  u32 r;
  asm("v_cvt_pk_bf16_f32 %0, %1, %2" : "=v"(r) : "v"(lo), "v"(hi));
  return r;
}

__device__ __forceinline__ float fexp2(float x) {
  float r;
  asm("v_exp_f32 %0, %1" : "=v"(r) : "v"(x));
  return r;
}

// ---------------- convert fp32 -> bf16, WEIGHTS ONLY (Wq,Wk,Wv,Wo) ---------------------
__global__ __launch_bounds__(256) void convert_w(
    const float* __restrict__ wq, const float* __restrict__ wk,
    const float* __restrict__ wv, const float* __restrict__ wo,
    u16* __restrict__ dst)   // = Wqb base
{
  int b = blockIdx.x, t = threadIdx.x;
  int w = b >> 9;
  const float* sp = (w == 0) ? wq : ((w == 1) ? wk : ((w == 2) ? wv : wo));
  size_t lb = (size_t)(b & 511) * 2048 + (size_t)t * 8;
  f32x4 f0 = *(const f32x4*)(sp + lb);
  f32x4 f1 = *(const f32x4*)(sp + lb + 4);
  u16x8 o;
  o[0]=f2bf(f0[0]); o[1]=f2bf(f0[1]); o[2]=f2bf(f0[2]); o[3]=f2bf(f0[3]);
  o[4]=f2bf(f1[0]); o[5]=f2bf(f1[1]); o[6]=f2bf(f1[2]); o[7]=f2bf(f1[3]);
  *(u16x8*)(dst + (size_t)b*2048 + (size_t)t*8) = o;
}

// ---------------- fused QKV GEMM, 128x128, BK=32, ring-3, fp32-A fused convert ---------
// (r11 version, frozen)
__global__ __launch_bounds__(256, 3) void gemm_qkv(
    const float* __restrict__ Xq, const float* __restrict__ Xk, const float* __restrict__ Xv,
    const u16* __restrict__ Wall,   // [3][1024][1024] bf16 (Wq,Wk,Wv)
    const float* __restrict__ bq, const float* __restrict__ bk, const float* __restrict__ bv,
    u16* __restrict__ Cqk, u16* __restrict__ VT)
{
  __shared__ __align__(16) u16 lds[24576];   // 3 x 8192 u16 (A:[0,4096) B:[4096,8192))
  const int t = threadIdx.x;
  const int wid = t >> 6, l = t & 63;
  const int c = l & 15, g = l >> 4;
  const int u = blockIdx.x;
  const int lid = (u & 7) * 96 + (u >> 3);
  const int which = lid >> 8;               // 256 tiles per which
  const int r5 = lid & 255;
  const int m0 = (r5 >> 3) * 128, n0 = (r5 & 7) * 128;
  const float* Afp = (which == 0) ? Xq : ((which == 1) ? Xk : Xv);
  const u16* Bw = Wall + (size_t)which * 1048576;
  const int wr = wid >> 1, wc = wid & 1;

  const int srow = wid*16 + (l >> 2);
  const int gch = ((l & 3) ^ (srow & 3) ^ ((srow >> 2) & 3)) << 3;
  const float* Ag0 = Afp + (size_t)(m0 + srow)*1024      + gch;
  const float* Ag1 = Afp + (size_t)(m0 + 64 + srow)*1024 + gch;
  const int awr0 = wid*512 + l*8;
  const int awr1 = 2048 + wid*512 + l*8;
  const u16* Bsrc0 = Bw + (size_t)(n0 + srow)*1024      + gch;
  const u16* Bsrc1 = Bw + (size_t)(n0 + 64 + srow)*1024 + gch;
  const int wbase = wid * 512;

  f32x4 ra0, ra1, ra2, ra3;

#define A_LOAD(j) do { \
    const float* ap0_ = Ag0 + ((j) << 5); \
    const float* ap1_ = Ag1 + ((j) << 5); \
    ra0 = *(const f32x4*)ap0_; ra1 = *(const f32x4*)(ap0_ + 4); \
    ra2 = *(const f32x4*)ap1_; ra3 = *(const f32x4*)(ap1_ + 4); \
  } while (0)

#define A_CVT_WRITE(j) do { \
    const int bo_ = ((j) % 3) * 8192; \
    u16x8 w0_, w1_; u32* q0_ = (u32*)&w0_; u32* q1_ = (u32*)&w1_; \
    q0_[0]=cvt_pk_bf16(ra0[0],ra0[1]); q0_[1]=cvt_pk_bf16(ra0[2],ra0[3]); \
    q0_[2]=cvt_pk_bf16(ra1[0],ra1[1]); q0_[3]=cvt_pk_bf16(ra1[2],ra1[3]); \
    q1_[0]=cvt_pk_bf16(ra2[0],ra2[1]); q1_[1]=cvt_pk_bf16(ra2[2],ra2[3]); \
    q1_[2]=cvt_pk_bf16(ra3[0],ra3[1]); q1_[3]=cvt_pk_bf16(ra3[2],ra3[3]); \
    *(u16x8*)&lds[bo_ + awr0] = w0_; \
    *(u16x8*)&lds[bo_ + awr1] = w1_; \
  } while (0)

#define B_STAGE(j) do { \
    const int bo_ = ((j) % 3) * 8192; const int ko_ = (j) << 5; \
    gload_lds16(Bsrc0 + ko_, &lds[bo_ + 4096 + wbase]); \
    gload_lds16(Bsrc1 + ko_, &lds[bo_ + 6144 + wbase]); \
  } while (0)

  const int fswz = (g ^ (c & 3) ^ ((c >> 2) & 3)) << 3;
  const int abase = (wr*64 + c)*32 + fswz;          // + mf*512
  const int bbase = 4096 + (wc*64 + c)*32 + fswz;   // + nf*512

  f32x4 acc[4][4] = {};

  A_LOAD(0);
  B_STAGE(0);
  B_STAGE(1);
  asm volatile("s_waitcnt vmcnt(2)" ::: "memory");
  A_CVT_WRITE(0);
  A_LOAD(1);
  asm volatile("s_waitcnt lgkmcnt(0)" ::: "memory");
  __builtin_amdgcn_s_barrier();
  __builtin_amdgcn_sched_barrier(0);

#pragma unroll
  for (int tstep = 0; tstep < 32; ++tstep) {
    if (tstep + 2 < 32) B_STAGE(tstep + 2);
    const int bo = (tstep % 3) * 8192;
    bf16x8 af[4], bf[4];
#pragma unroll
    for (int mf = 0; mf < 4; ++mf)
      af[mf] = *(const bf16x8*)&lds[bo + abase + mf*512];
#pragma unroll
    for (int nf = 0; nf < 4; ++nf)
      bf[nf] = *(const bf16x8*)&lds[bo + bbase + nf*512];
    __builtin_amdgcn_s_setprio(1);
#pragma unroll
    for (int mf = 0; mf < 4; ++mf)
#pragma unroll
      for (int nf = 0; nf < 4; ++nf)
        acc[mf][nf] = __builtin_amdgcn_mfma_f32_16x16x32_bf16(af[mf], bf[nf], acc[mf][nf], 0, 0, 0);
    __builtin_amdgcn_s_setprio(0);
    if (tstep + 1 < 32) {
      if (tstep + 2 < 32) asm volatile("s_waitcnt vmcnt(2)" ::: "memory");
      else                asm volatile("s_waitcnt vmcnt(0)" ::: "memory");
      A_CVT_WRITE(tstep + 1);
      if (tstep + 2 < 32) A_LOAD(tstep + 2);
    }
    asm volatile("s_waitcnt lgkmcnt(0)" ::: "memory");
    __builtin_amdgcn_s_barrier();
    __builtin_amdgcn_sched_barrier(0);
  }
#undef A_LOAD
#undef A_CVT_WRITE
#undef B_STAGE

  const float* bias = (which == 0) ? bq : ((which == 1) ? bk : bv);
  if (which < 2) {
#pragma unroll
    for (int mf = 0; mf < 4; ++mf)
#pragma unroll
      for (int nf = 0; nf < 4; ++nf) {
        int row = m0 + wr*64 + mf*16 + g*4;
        int col = n0 + wc*64 + nf*16 + c;
        float bv_ = bias[col];
        int colg = which*1024 + col;
#pragma unroll
        for (int r = 0; r < 4; ++r)
          Cqk[(size_t)(row+r)*2048 + colg] = f2bf(acc[mf][nf][r] + bv_);
      }
  } else {
#pragma unroll
    for (int mf = 0; mf < 4; ++mf)
#pragma unroll
      for (int nf = 0; nf < 4; ++nf) {
        int row = m0 + wr*64 + mf*16 + g*4;
        int col = n0 + wc*64 + nf*16 + c;
        float bv_ = bias[col];
        int bb2 = row >> 11, s = row & 2047;
        int hh = col >> 6, dh = col & 63;
        u16x4 pk;
#pragma unroll
        for (int r = 0; r < 4; ++r) pk[r] = f2bf(acc[mf][nf][r] + bv_);
        *(u16x4*)&VT[((size_t)(((bb2<<4)+hh)<<6) + dh)*2048 + s] = pk;
      }
  }
}

// ---------------- GEMM out = AO * Wo^T + bo, 128x64, BK=32, ring-3, 512 blocks ---------
// (r15 version, frozen)
__global__ __launch_bounds__(256, 2) void gemm_out(
    const u16* __restrict__ A, const u16* __restrict__ Bw,
    const float* __restrict__ bias, float* __restrict__ C)
{
  __shared__ __align__(16) u16 lds[18432];   // 3 x 6144 u16
  const int t = threadIdx.x;
  const int wid = t >> 6, l = t & 63;
  const int c = l & 15, g = l >> 4;
  const int u = blockIdx.x;
  const int lid = (u & 7) * 64 + (u >> 3);
  const int m0 = (lid >> 4) * 128, n0 = (lid & 15) * 64;
  const int wr = wid >> 1, wc = wid & 1;

  const int srow = wid*16 + (l >> 2);
  const int sswz = (((l & 3) ^ (srow & 3) ^ ((srow >> 2) & 3)) << 3);
  const u16* Asrc0 = A  + (size_t)(m0 + srow)*1024      + sswz;
  const u16* Asrc1 = A  + (size_t)(m0 + 64 + srow)*1024 + sswz;
  const u16* Bsrc0 = Bw + (size_t)(n0 + srow)*1024      + sswz;
  const int wbase = wid * 512;

#define O_STAGE(j) do { \
    const int bo_ = ((j) % 3) * 6144; const int ko_ = (j) << 5; \
    gload_lds16(Asrc0 + ko_, &lds[bo_ + wbase]); \
    gload_lds16(Asrc1 + ko_, &lds[bo_ + 2048 + wbase]); \
    gload_lds16(Bsrc0 + ko_, &lds[bo_ + 4096 + wbase]); \
  } while (0)

  const int fswz = (g ^ (c & 3) ^ ((c >> 2) & 3)) << 3;
  const int abase = (wr*64 + c)*32 + fswz;
  const int bbase = 4096 + (wc*32 + c)*32 + fswz;

  f32x4 acc[4][2] = {};

  O_STAGE(0);
  O_STAGE(1);
  asm volatile("s_waitcnt vmcnt(3)" ::: "memory");
  __builtin_amdgcn_s_barrier();
  __builtin_amdgcn_sched_barrier(0);

#pragma unroll
  for (int tstep = 0; tstep < 32; ++tstep) {
    if (tstep + 2 < 32) O_STAGE(tstep + 2);
    const int bo = (tstep % 3) * 6144;
    bf16x8 af[4], bf[2];
#pragma unroll
    for (int mf = 0; mf < 4; ++mf)
      af[mf] = *(const bf16x8*)&lds[bo + abase + mf*512];
#pragma unroll
    for (int nf = 0; nf < 2; ++nf)
      bf[nf] = *(const bf16x8*)&lds[bo + bbase + nf*512];
    __builtin_amdgcn_s_setprio(1);
#pragma unroll
    for (int mf = 0; mf < 4; ++mf)
#pragma unroll
      for (int nf = 0; nf < 2; ++nf)
        acc[mf][nf] = __builtin_amdgcn_mfma_f32_16x16x32_bf16(af[mf], bf[nf], acc[mf][nf], 0, 0, 0);
    __builtin_amdgcn_s_setprio(0);
    if (tstep + 2 < 32) asm volatile("s_waitcnt vmcnt(3)" ::: "memory");
    else                asm volatile("s_waitcnt vmcnt(0)" ::: "memory");
    __builtin_amdgcn_s_barrier();
    __builtin_amdgcn_sched_barrier(0);
  }
#undef O_STAGE

#pragma unroll
  for (int mf = 0; mf < 4; ++mf)
#pragma unroll
    for (int nf = 0; nf < 2; ++nf) {
      int row = m0 + wr*64 + mf*16 + g*4;
      int col = n0 + wc*32 + nf*16 + c;
      float bv_ = bias[col];
#pragma unroll
      for (int r = 0; r < 4; ++r)
        C[(size_t)(row+r)*1024 + col] = acc[mf][nf][r] + bv_;
    }
}

// ---------------- causal flash attention, split-KV, DH=64, QBLK=64, KVBLK=64 -----------
// Round 16: V fragments direct from global (L2-resident VT, XCD-chunked) — removes the
// 4x-duplicated V LDS reads (8 b128/iter/wave) and V staging. LDS 24KB (Q/P + K dbuf);
// occupancy stays 4/CU (grid-limited), bound stays 4 (VGPR cap 64 — no r14 clamp).
__device__ __forceinline__ void stage_k(u16* lds, const u16* Kt, int buf, int wid) {
#pragma unroll
  for (int ii = 0; ii < 2; ++ii)
    gload_lds16(Kt + (size_t)ii*32*2048, &lds[4096 + buf*4096 + ii*2048 + wid*512]);
}

__device__ __forceinline__ void attn_phase(
    u16* lds, const u16* Qg, const u16* Ka, const u16* Vl,
    int q0, int kt0, int nkv, bool maskLast,
    int wid, int g, int c, int arow, int achk, int pbase, int cs,
    float& MI, float& LI, f32x4 (&o)[4])
{
  const float SC = 0.18033688f;  // (1/8) * log2(e)
  // stage Q tile [64][64] swizzled
#pragma unroll
  for (int i = 0; i < 2; ++i) {
    int row = i*32 + arow;
    gload_lds16(Qg + (size_t)(q0+row)*2048 + ((achk ^ (row&7)) << 3),
                &lds[i*2048 + wid*512]);
  }
  const u16* Kt = Ka + (size_t)kt0 * (64*2048);
  const u16* Vp = Vl + kt0 * 64;
  stage_k(lds, Kt, 0, wid);
  asm volatile("s_waitcnt vmcnt(0)" ::: "memory");
  __builtin_amdgcn_s_barrier();
  __builtin_amdgcn_sched_barrier(0);

  bf16x8 qf[2];
#pragma unroll
  for (int kh = 0; kh < 2; ++kh) {
    int row = wid*16 + c;
    int ch = (kh*4 + g) ^ (row & 7);
    qf[kh] = *(const bf16x8*)&lds[row*64 + ch*8];
  }

  float mi = -INFINITY, li = 0.f;
#pragma unroll
  for (int df = 0; df < 4; ++df) o[df] = f32x4{0.f, 0.f, 0.f, 0.f};

  for (int i = 0; i < nkv; ++i) {
    if (i + 1 < nkv) {
      Kt += 64*2048;
      stage_k(lds, Kt, (i+1)&1, wid);
    }
    const u16* Kb = &lds[4096 + (i&1)*4096];

    // QK^T swapped: lane holds q = c, k = 16nf + 4g + r
    f32x4 sT[4] = {};
    __builtin_amdgcn_s_setprio(1);
#pragma unroll
    for (int kh = 0; kh < 2; ++kh) {
      bf16x8 kf[4];
#pragma unroll
      for (int nf = 0; nf < 4; ++nf) {
        int row = nf*16 + c;
        int ch = (kh*4 + g) ^ (c & 7);
        kf[nf] = *(const bf16x8*)&Kb[row*64 + ch*8];
      }
#pragma unroll
      for (int nf = 0; nf < 4; ++nf)
        sT[nf] = __builtin_amdgcn_mfma_f32_16x16x32_bf16(kf[nf], qf[kh], sT[nf], 0,0,0);
    }
    __builtin_amdgcn_s_setprio(0);

    if (maskLast && i == nkv - 1) {   // diagonal causal mask
#pragma unroll
      for (int nf = 0; nf < 4; ++nf)
#pragma unroll
        for (int r = 0; r < 4; ++r)
          if (nf*16 + g*4 + r > wid*16 + c) sT[nf][r] = -INFINITY;
    }

    // defer-max online softmax
    float mx = fmaxf(fmaxf(sT[0][0], sT[0][1]), fmaxf(sT[0][2], sT[0][3]));
#pragma unroll
    for (int nf = 1; nf < 4; ++nf)
      mx = fmaxf(mx, fmaxf(fmaxf(sT[nf][0], sT[nf][1]), fmaxf(sT[nf][2], sT[nf][3])));
    if (!__all(mx * SC <= mi + 8.f)) {
      float mxr = fmaxf(mx, __shfl_xor(mx, 16, 64));
      mxr = fmaxf(mxr, __shfl_xor(mxr, 32, 64));
      float mn = fmaxf(mi, mxr * SC);
      float corr = fexp2(mi - mn);
      li *= corr;
#pragma unroll
      for (int df = 0; df < 4; ++df) {
        o[df][0] *= corr; o[df][1] *= corr;
        o[df][2] *= corr; o[df][3] *= corr;
      }
      mi = mn;
    }
    float sum = 0.f;
#pragma unroll
    for (int nf = 0; nf < 4; ++nf)
#pragma unroll
      for (int r = 0; r < 4; ++r) {
        float pv = fexp2(fmaf(sT[nf][r], SC, -mi));
        sT[nf][r] = pv;
        sum += pv;
      }
    li += sum;

    // V kh=0 fragments direct from global (L2); consumed after P round-trip
    bf16x8 vfa[4];
#pragma unroll
    for (int df = 0; df < 4; ++df)
      vfa[df] = *(const bf16x8*)(Vp + (size_t)df*32768);

    // P -> LDS (wave-private), packed bf16 via cvt_pk + b64 writes
#pragma unroll
    for (int nf = 0; nf < 4; ++nf) {
      u32x2 ww;
      ww[0] = cvt_pk_bf16(sT[nf][0], sT[nf][1]);
      ww[1] = cvt_pk_bf16(sT[nf][2], sT[nf][3]);
      int ch = (2*nf + (g >> 1)) ^ cs;
      *(u32x2*)&lds[pbase + c*64 + ch*8 + (g & 1)*4] = ww;
    }

    // V kh=1 fragments
    bf16x8 vfb[4];
#pragma unroll
    for (int df = 0; df < 4; ++df)
      vfb[df] = *(const bf16x8*)(Vp + (size_t)df*32768 + 32);

    asm volatile("s_waitcnt lgkmcnt(0)" ::: "memory");
    __builtin_amdgcn_sched_barrier(0);

    // PV swapped: o[df] = V^T-frag x P-frag -> O^T[d][q = c]
    __builtin_amdgcn_s_setprio(1);
    {
      bf16x8 pfr;
      { int ch = g ^ cs; pfr = *(const bf16x8*)&lds[pbase + c*64 + ch*8]; }
#pragma unroll
      for (int df = 0; df < 4; ++df)
        o[df] = __builtin_amdgcn_mfma_f32_16x16x32_bf16(vfa[df], pfr, o[df], 0,0,0);
      { int ch = (4 + g) ^ cs; pfr = *(const bf16x8*)&lds[pbase + c*64 + ch*8]; }
#pragma unroll
      for (int df = 0; df < 4; ++df)
        o[df] = __builtin_amdgcn_mfma_f32_16x16x32_bf16(vfb[df], pfr, o[df], 0,0,0);
    }
    __builtin_amdgcn_s_setprio(0);

    asm volatile("s_waitcnt vmcnt(0)" ::: "memory");  // next K tile landed
    __builtin_amdgcn_s_barrier();                     // all done reading cur K buf
    __builtin_amdgcn_sched_barrier(0);
    Vp += 64;
  }
  MI = mi; LI = li;
}

// partial layout (u16 units, stride 4608): [0,4096) o bf16 [64][64];
// [4096,4224) m f32[64]; [4224,4352) l f32[64]; [4352,4608) pad.
__device__ __forceinline__ void store_partial(
    u16* __restrict__ part, int slot, int s,
    int wid, int g, int c, float mi, float li_tot, const f32x4 (&o)[4])
{
  u16* po = part + (size_t)(slot*2 + s) * 4608;
  int q = wid*16 + c;
#pragma unroll
  for (int df = 0; df < 4; ++df) {
    u16x4 pk;
    pk[0] = f2bf(o[df][0]); pk[1] = f2bf(o[df][1]);
    pk[2] = f2bf(o[df][2]); pk[3] = f2bf(o[df][3]);
    *(u16x4*)&po[q*64 + df*16 + g*4] = pk;
  }
  if (g == 0) {
    ((float*)(po + 4096))[q] = mi;
    ((float*)(po + 4224))[q] = li_tot;
  }
}

__global__ __launch_bounds__(256, 4) void attn_fwd(
    const u16* __restrict__ QK, const u16* __restrict__ VT,
    u16* __restrict__ AO, u16* __restrict__ part)
{
  // u16 units: [0,4096) Q staging / per-wave P; [4096,12288) K dbuf.  24 KB.
  __shared__ __align__(16) u16 lds[12288];
  const int t = threadIdx.x;
  const int wid = t >> 6, l = t & 63;
  const int g = l >> 4, c = l & 15;
  const int u = blockIdx.x;
  const int lid = (u & 7) * 128 + (u >> 3);
  const int gx = lid & 31, h = (lid >> 5) & 15, b = lid >> 9;
  const int p = gx >> 1, s = gx & 1;
  const u16* Qg  = QK + (size_t)b * 2048 * 2048 + (size_t)h * 64;
  const u16* Kg  = Qg + 1024;
  const u16* VTg = VT + (size_t)(((b << 4) + h) << 6) * 2048;
  const int arow = t >> 3, achk = t & 7;
  const int pbase = wid * 1024;
  const int cs = (c & 7) ^ ((c >> 3) << 2);
  const u16* Ka = Kg  + (size_t)arow*2048 + ((achk ^ (arow & 7)) << 3);
  const u16* Vl = VTg + (size_t)c*2048 + g*8;
  const int slot = ((b*16 + h)*16 + p);

  float mi, li; f32x4 o[4];

  if (s == 0) {
    attn_phase(lds, Qg, Ka, Vl, p*64, 0, p+1, true,
               wid, g, c, arow, achk, pbase, cs, mi, li, o);
    {
      float lt = li + __shfl_xor(li, 16, 64);
      lt += __shfl_xor(lt, 32, 64);
      float nr = 1.f / lt;
      int row = p*64 + wid*16 + c;
      size_t rb = ((size_t)b*2048 + row)*1024 + h*64;
#pragma unroll
      for (int df = 0; df < 4; ++df) {
        u16x4 pk;
        pk[0] = f2bf(o[df][0] * nr); pk[1] = f2bf(o[df][1] * nr);
        pk[2] = f2bf(o[df][2] * nr); pk[3] = f2bf(o[df][3] * nr);
        *(u16x4*)&AO[rb + df*16 + g*4] = pk;
      }
    }
    attn_phase(lds, Qg, Ka, Vl, (31-p)*64, 0, 16-p, false,
               wid, g, c, arow, achk, pbase, cs, mi, li, o);
    float lt = li + __shfl_xor(li, 16, 64);
    lt += __shfl_xor(lt, 32, 64);
    store_partial(part, slot, 0, wid, g, c, mi, lt, o);
  } else {
    attn_phase(lds, Qg, Ka, Vl, (31-p)*64, 16-p, 16, true,
               wid, g, c, arow, achk, pbase, cs, mi, li, o);
    float lt = li + __shfl_xor(li, 16, 64);
    lt += __shfl_xor(lt, 32, 64);
    store_partial(part, slot, 1, wid, g, c, mi, lt, o);
  }
}

// ---------------- merge the two partials of q-tiles 16..31 (bf16 partials) -------------
__global__ __launch_bounds__(256) void attn_merge(
    const u16* __restrict__ part, u16* __restrict__ AO)
{
  int slot = blockIdx.x;
  int p = slot & 15;
  int h = (slot >> 4) & 15;
  int b = slot >> 8;
  const u16* p0 = part + (size_t)slot * 9216;
  const u16* p1 = p0 + 4608;
  int t = threadIdx.x;
  int r = t >> 2, c0 = (t & 3) * 16;
  float m0 = ((const float*)(p0 + 4096))[r], m1 = ((const float*)(p1 + 4096))[r];
  float l0 = ((const float*)(p0 + 4224))[r], l1 = ((const float*)(p1 + 4224))[r];
  float m = fmaxf(m0, m1);
  float e0 = exp2f(m0 - m), e1 = exp2f(m1 - m);
  float rl = 1.f / (l0*e0 + l1*e1);
  e0 *= rl; e1 *= rl;
  const u16x8* a0 = (const u16x8*)(p0 + r*64 + c0);
  const u16x8* a1 = (const u16x8*)(p1 + r*64 + c0);
  int qrow = (31 - p)*64 + r;
  size_t ab = ((size_t)b*2048 + qrow)*1024 + h*64 + c0;
#pragma unroll
  for (int half = 0; half < 2; ++half) {
    u16x8 x = a0[half], y = a1[half];
    u16x8 w;
#pragma unroll
    for (int j = 0; j < 8; ++j)
      w[j] = f2bf(bf2f(x[j])*e0 + bf2f(y[j])*e1);
    *(u16x8*)&AO[ab + half*8] = w;
  }
}

// ---------------------------------------------------------------------------------------
extern "C" void kernel_launch(void* const* d_in, const int* in_sizes, int n_in,
                              void* d_out, int out_size, void* d_ws, size_t ws_size,
                              hipStream_t stream)
{
  const float* q  = (const float*)d_in[0];
  const float* k  = (const float*)d_in[1];
  const float* v  = (const float*)d_in[2];
  // d_in[3] = mask (causal tril; applied analytically)
  const float* Wq = (const float*)d_in[4];
  const float* bq = (const float*)d_in[5];
  const float* Wk = (const float*)d_in[6];
  const float* bk = (const float*)d_in[7];
  const float* Wv = (const float*)d_in[8];
  const float* bv = (const float*)d_in[9];
  const float* Wo = (const float*)d_in[10];
  const float* bo = (const float*)d_in[11];
  float* out = (float*)d_out;

  u16* ws   = (u16*)d_ws;
  // [0 .. 12.6M): attn partial buffer (bf16 o + f32 m/l)
  u16* Wqb  = ws + 12582912;      // [3][1024][1024] bf16 weights (Wq,Wk,Wv)
  u16* Wob  = ws + 15728640;      // [1024][1024]
  u16* QKp  = ws + 16777216;      // [4096][2048]  (Q | K)
  u16* VTp  = ws + 25165824;      // [2][16][64][2048]  V transposed
  u16* AO   = ws + 29360128;      // [4096][1024]

  convert_w<<<2048, 256, 0, stream>>>(Wq, Wk, Wv, Wo, Wqb);

  gemm_qkv<<<768, 256, 0, stream>>>(q, k, v, Wqb, bq, bk, bv, QKp, VTp);

  attn_fwd<<<1024, 256, 0, stream>>>(QKp, VTp, AO, ws);

  attn_merge<<<512, 256, 0, stream>>>(ws, AO);

  gemm_out<<<512, 256, 0, stream>>>(AO, Wob, bo, out);
}

// Round 17
// 101.312 us; speedup vs baseline: 1.3636x; 1.3636x over previous
//
#include <hip/hip_runtime.h>

typedef unsigned int u32;
typedef unsigned short u16;
typedef __attribute__((ext_vector_type(8))) short bf16x8;
typedef __attribute__((ext_vector_type(8))) u16 u16x8;
typedef __attribute__((ext_vector_type(4))) u16 u16x4;
typedef __attribute__((ext_vector_type(4))) float f32x4;
typedef __attribute__((ext_vector_type(2))) u32 u32x2;

#define AS1 __attribute__((address_space(1)))
#define AS3 __attribute__((address_space(3)))

__device__ __forceinline__ void gload_lds16(const void* g, void* l) {
  __builtin_amdgcn_global_load_lds((const AS1 u32*)g, (AS3 u32*)l, 16, 0, 0);
}

__device__ __forceinline__ u16 f2bf(float f) {
  union { float f; u32 u; } x; x.f = f;
  u32 u = x.u;
  return (u16)((u + 0x7fffu + ((u >> 16) & 1u)) >> 16);
}

__device__ __forceinline__ float bf2f(u16 v) {
  union { u32 u; float f; } x; x.u = (u32)v << 16; return x.f;
}

__device__ __forceinline__ u32 cvt_pk_bf16(float lo, float hi) {
  u32 r;
  asm("v_cvt_pk_bf16_f32 %0, %1, %2" : "=v"(r) : "v"(lo), "v"(hi));
  return r;
}

__device__ __forceinline__ float fexp2(float x) {
  float r;
  asm("v_exp_f32 %0, %1" : "=v"(r) : "v"(x));
  return r;
}

// ---------------- convert fp32 -> bf16, WEIGHTS ONLY (Wq,Wk,Wv,Wo) ---------------------
__global__ __launch_bounds__(256) void convert_w(
    const float* __restrict__ wq, const float* __restrict__ wk,
    const float* __restrict__ wv, const float* __restrict__ wo,
    u16* __restrict__ dst)   // = Wqb base
{
  int b = blockIdx.x, t = threadIdx.x;
  int w = b >> 9;
  const float* sp = (w == 0) ? wq : ((w == 1) ? wk : ((w == 2) ? wv : wo));
  size_t lb = (size_t)(b & 511) * 2048 + (size_t)t * 8;
  f32x4 f0 = *(const f32x4*)(sp + lb);
  f32x4 f1 = *(const f32x4*)(sp + lb + 4);
  u16x8 o;
  o[0]=f2bf(f0[0]); o[1]=f2bf(f0[1]); o[2]=f2bf(f0[2]); o[3]=f2bf(f0[3]);
  o[4]=f2bf(f1[0]); o[5]=f2bf(f1[1]); o[6]=f2bf(f1[2]); o[7]=f2bf(f1[3]);
  *(u16x8*)(dst + (size_t)b*2048 + (size_t)t*8) = o;
}

// ---------------- fused QKV GEMM, 128x128, BK=32, ring-3, fp32-A fused convert ---------
// (r11 version, frozen — best-measured family)
__global__ __launch_bounds__(256, 3) void gemm_qkv(
    const float* __restrict__ Xq, const float* __restrict__ Xk, const float* __restrict__ Xv,
    const u16* __restrict__ Wall,   // [3][1024][1024] bf16 (Wq,Wk,Wv)
    const float* __restrict__ bq, const float* __restrict__ bk, const float* __restrict__ bv,
    u16* __restrict__ Cqk, u16* __restrict__ VT)
{
  __shared__ __align__(16) u16 lds[24576];   // 3 x 8192 u16 (A:[0,4096) B:[4096,8192))
  const int t = threadIdx.x;
  const int wid = t >> 6, l = t & 63;
  const int c = l & 15, g = l >> 4;
  const int u = blockIdx.x;
  const int lid = (u & 7) * 96 + (u >> 3);
  const int which = lid >> 8;               // 256 tiles per which
  const int r5 = lid & 255;
  const int m0 = (r5 >> 3) * 128, n0 = (r5 & 7) * 128;
  const float* Afp = (which == 0) ? Xq : ((which == 1) ? Xk : Xv);
  const u16* Bw = Wall + (size_t)which * 1048576;
  const int wr = wid >> 1, wc = wid & 1;

  const int srow = wid*16 + (l >> 2);
  const int gch = ((l & 3) ^ (srow & 3) ^ ((srow >> 2) & 3)) << 3;
  const float* Ag0 = Afp + (size_t)(m0 + srow)*1024      + gch;
  const float* Ag1 = Afp + (size_t)(m0 + 64 + srow)*1024 + gch;
  const int awr0 = wid*512 + l*8;
  const int awr1 = 2048 + wid*512 + l*8;
  const u16* Bsrc0 = Bw + (size_t)(n0 + srow)*1024      + gch;
  const u16* Bsrc1 = Bw + (size_t)(n0 + 64 + srow)*1024 + gch;
  const int wbase = wid * 512;

  f32x4 ra0, ra1, ra2, ra3;

#define A_LOAD(j) do { \
    const float* ap0_ = Ag0 + ((j) << 5); \
    const float* ap1_ = Ag1 + ((j) << 5); \
    ra0 = *(const f32x4*)ap0_; ra1 = *(const f32x4*)(ap0_ + 4); \
    ra2 = *(const f32x4*)ap1_; ra3 = *(const f32x4*)(ap1_ + 4); \
  } while (0)

#define A_CVT_WRITE(j) do { \
    const int bo_ = ((j) % 3) * 8192; \
    u16x8 w0_, w1_; u32* q0_ = (u32*)&w0_; u32* q1_ = (u32*)&w1_; \
    q0_[0]=cvt_pk_bf16(ra0[0],ra0[1]); q0_[1]=cvt_pk_bf16(ra0[2],ra0[3]); \
    q0_[2]=cvt_pk_bf16(ra1[0],ra1[1]); q0_[3]=cvt_pk_bf16(ra1[2],ra1[3]); \
    q1_[0]=cvt_pk_bf16(ra2[0],ra2[1]); q1_[1]=cvt_pk_bf16(ra2[2],ra2[3]); \
    q1_[2]=cvt_pk_bf16(ra3[0],ra3[1]); q1_[3]=cvt_pk_bf16(ra3[2],ra3[3]); \
    *(u16x8*)&lds[bo_ + awr0] = w0_; \
    *(u16x8*)&lds[bo_ + awr1] = w1_; \
  } while (0)

#define B_STAGE(j) do { \
    const int bo_ = ((j) % 3) * 8192; const int ko_ = (j) << 5; \
    gload_lds16(Bsrc0 + ko_, &lds[bo_ + 4096 + wbase]); \
    gload_lds16(Bsrc1 + ko_, &lds[bo_ + 6144 + wbase]); \
  } while (0)

  const int fswz = (g ^ (c & 3) ^ ((c >> 2) & 3)) << 3;
  const int abase = (wr*64 + c)*32 + fswz;          // + mf*512
  const int bbase = 4096 + (wc*64 + c)*32 + fswz;   // + nf*512

  f32x4 acc[4][4] = {};

  A_LOAD(0);
  B_STAGE(0);
  B_STAGE(1);
  asm volatile("s_waitcnt vmcnt(2)" ::: "memory");
  A_CVT_WRITE(0);
  A_LOAD(1);
  asm volatile("s_waitcnt lgkmcnt(0)" ::: "memory");
  __builtin_amdgcn_s_barrier();
  __builtin_amdgcn_sched_barrier(0);

#pragma unroll
  for (int tstep = 0; tstep < 32; ++tstep) {
    if (tstep + 2 < 32) B_STAGE(tstep + 2);
    const int bo = (tstep % 3) * 8192;
    bf16x8 af[4], bf[4];
#pragma unroll
    for (int mf = 0; mf < 4; ++mf)
      af[mf] = *(const bf16x8*)&lds[bo + abase + mf*512];
#pragma unroll
    for (int nf = 0; nf < 4; ++nf)
      bf[nf] = *(const bf16x8*)&lds[bo + bbase + nf*512];
    __builtin_amdgcn_s_setprio(1);
#pragma unroll
    for (int mf = 0; mf < 4; ++mf)
#pragma unroll
      for (int nf = 0; nf < 4; ++nf)
        acc[mf][nf] = __builtin_amdgcn_mfma_f32_16x16x32_bf16(af[mf], bf[nf], acc[mf][nf], 0, 0, 0);
    __builtin_amdgcn_s_setprio(0);
    if (tstep + 1 < 32) {
      if (tstep + 2 < 32) asm volatile("s_waitcnt vmcnt(2)" ::: "memory");
      else                asm volatile("s_waitcnt vmcnt(0)" ::: "memory");
      A_CVT_WRITE(tstep + 1);
      if (tstep + 2 < 32) A_LOAD(tstep + 2);
    }
    asm volatile("s_waitcnt lgkmcnt(0)" ::: "memory");
    __builtin_amdgcn_s_barrier();
    __builtin_amdgcn_sched_barrier(0);
  }
#undef A_LOAD
#undef A_CVT_WRITE
#undef B_STAGE

  const float* bias = (which == 0) ? bq : ((which == 1) ? bk : bv);
  if (which < 2) {
#pragma unroll
    for (int mf = 0; mf < 4; ++mf)
#pragma unroll
      for (int nf = 0; nf < 4; ++nf) {
        int row = m0 + wr*64 + mf*16 + g*4;
        int col = n0 + wc*64 + nf*16 + c;
        float bv_ = bias[col];
        int colg = which*1024 + col;
#pragma unroll
        for (int r = 0; r < 4; ++r)
          Cqk[(size_t)(row+r)*2048 + colg] = f2bf(acc[mf][nf][r] + bv_);
      }
  } else {
#pragma unroll
    for (int mf = 0; mf < 4; ++mf)
#pragma unroll
      for (int nf = 0; nf < 4; ++nf) {
        int row = m0 + wr*64 + mf*16 + g*4;
        int col = n0 + wc*64 + nf*16 + c;
        float bv_ = bias[col];
        int bb2 = row >> 11, s = row & 2047;
        int hh = col >> 6, dh = col & 63;
        u16x4 pk;
#pragma unroll
        for (int r = 0; r < 4; ++r) pk[r] = f2bf(acc[mf][nf][r] + bv_);
        *(u16x4*)&VT[((size_t)(((bb2<<4)+hh)<<6) + dh)*2048 + s] = pk;
      }
  }
}

// ---------------- GEMM out = AO * Wo^T + bo, 128x128, BK=32, ring-3, fp32 out ----------
// (r11 version, frozen)
__global__ __launch_bounds__(256, 3) void gemm_out(
    const u16* __restrict__ A, const u16* __restrict__ Bw,
    const float* __restrict__ bias, float* __restrict__ C)
{
  __shared__ __align__(16) u16 lds[24576];
  const int t = threadIdx.x;
  const int wid = t >> 6, l = t & 63;
  const int c = l & 15, g = l >> 4;
  const int u = blockIdx.x;
  const int lid = (u & 7) * 32 + (u >> 3);
  const int m0 = (lid >> 3) * 128, n0 = (lid & 7) * 128;
  const int wr = wid >> 1, wc = wid & 1;

  const int srow = wid*16 + (l >> 2);
  const int sswz = (((l & 3) ^ (srow & 3) ^ ((srow >> 2) & 3)) << 3);
  const u16* Asrc0 = A  + (size_t)(m0 + srow)*1024      + sswz;
  const u16* Asrc1 = A  + (size_t)(m0 + 64 + srow)*1024 + sswz;
  const u16* Bsrc0 = Bw + (size_t)(n0 + srow)*1024      + sswz;
  const u16* Bsrc1 = Bw + (size_t)(n0 + 64 + srow)*1024 + sswz;
  const int wbase = wid * 512;

#define O_STAGE(j) do { \
    const int bo_ = ((j) % 3) * 8192; const int ko_ = (j) << 5; \
    gload_lds16(Asrc0 + ko_, &lds[bo_ + wbase]); \
    gload_lds16(Asrc1 + ko_, &lds[bo_ + 2048 + wbase]); \
    gload_lds16(Bsrc0 + ko_, &lds[bo_ + 4096 + wbase]); \
    gload_lds16(Bsrc1 + ko_, &lds[bo_ + 6144 + wbase]); \
  } while (0)

  const int fswz = (g ^ (c & 3) ^ ((c >> 2) & 3)) << 3;
  const int abase = (wr*64 + c)*32 + fswz;
  const int bbase = 4096 + (wc*64 + c)*32 + fswz;

  f32x4 acc[4][4] = {};

  O_STAGE(0);
  O_STAGE(1);
  asm volatile("s_waitcnt vmcnt(4)" ::: "memory");
  __builtin_amdgcn_s_barrier();
  __builtin_amdgcn_sched_barrier(0);

#pragma unroll
  for (int tstep = 0; tstep < 32; ++tstep) {
    if (tstep + 2 < 32) O_STAGE(tstep + 2);
    const int bo = (tstep % 3) * 8192;
    bf16x8 af[4], bf[4];
#pragma unroll
    for (int mf = 0; mf < 4; ++mf)
      af[mf] = *(const bf16x8*)&lds[bo + abase + mf*512];
#pragma unroll
    for (int nf = 0; nf < 4; ++nf)
      bf[nf] = *(const bf16x8*)&lds[bo + bbase + nf*512];
    __builtin_amdgcn_s_setprio(1);
#pragma unroll
    for (int mf = 0; mf < 4; ++mf)
#pragma unroll
      for (int nf = 0; nf < 4; ++nf)
        acc[mf][nf] = __builtin_amdgcn_mfma_f32_16x16x32_bf16(af[mf], bf[nf], acc[mf][nf], 0, 0, 0);
    __builtin_amdgcn_s_setprio(0);
    if (tstep + 2 < 32) asm volatile("s_waitcnt vmcnt(4)" ::: "memory");
    else                asm volatile("s_waitcnt vmcnt(0)" ::: "memory");
    __builtin_amdgcn_s_barrier();
    __builtin_amdgcn_sched_barrier(0);
  }
#undef O_STAGE

#pragma unroll
  for (int mf = 0; mf < 4; ++mf)
#pragma unroll
    for (int nf = 0; nf < 4; ++nf) {
      int row = m0 + wr*64 + mf*16 + g*4;
      int col = n0 + wc*64 + nf*16 + c;
      float bv_ = bias[col];
#pragma unroll
      for (int r = 0; r < 4; ++r)
        C[(size_t)(row+r)*1024 + col] = acc[mf][nf][r] + bv_;
    }
}

// ---------------- causal flash attention, split-KV, DH=64, QBLK=64, KVBLK=64 -----------
// (r11/r13 proven attn: V-in-LDS, swapped QK^T + swapped PV, defer-max, lane-partial li)
__device__ __forceinline__ void stage_kv(u16* lds, const u16* Kt, const u16* Vt,
                                         int buf, int wid) {
#pragma unroll
  for (int ii = 0; ii < 2; ++ii)
    gload_lds16(Kt + (size_t)ii*32*2048, &lds[4096 + buf*4096 + ii*2048 + wid*512]);
#pragma unroll
  for (int ii = 0; ii < 2; ++ii)
    gload_lds16(Vt + (size_t)ii*32*2048, &lds[12288 + buf*4096 + ii*2048 + wid*512]);
}

__device__ __forceinline__ void attn_phase(
    u16* lds, const u16* Qg, const u16* Ka, const u16* Va,
    int q0, int kt0, int nkv, bool maskLast,
    int wid, int g, int c, int arow, int achk, int pbase, int cs,
    float& MI, float& LI, f32x4 (&o)[4])
{
  const float SC = 0.18033688f;  // (1/8) * log2(e)
#pragma unroll
  for (int i = 0; i < 2; ++i) {
    int row = i*32 + arow;
    gload_lds16(Qg + (size_t)(q0+row)*2048 + ((achk ^ (row&7)) << 3),
                &lds[i*2048 + wid*512]);
  }
  const u16* Kt = Ka + (size_t)kt0 * (64*2048);
  const u16* Vt = Va + kt0 * 64;
  stage_kv(lds, Kt, Vt, 0, wid);
  asm volatile("s_waitcnt vmcnt(0)" ::: "memory");
  __builtin_amdgcn_s_barrier();
  __builtin_amdgcn_sched_barrier(0);

  bf16x8 qf[2];
#pragma unroll
  for (int kh = 0; kh < 2; ++kh) {
    int row = wid*16 + c;
    int ch = (kh*4 + g) ^ (row & 7);
    qf[kh] = *(const bf16x8*)&lds[row*64 + ch*8];
  }

  float mi = -INFINITY, li = 0.f;
#pragma unroll
  for (int df = 0; df < 4; ++df) o[df] = f32x4{0.f, 0.f, 0.f, 0.f};

  for (int i = 0; i < nkv; ++i) {
    if (i + 1 < nkv) {
      Kt += 64*2048; Vt += 64;
      stage_kv(lds, Kt, Vt, (i+1)&1, wid);
    }
    const u16* Kb = &lds[4096  + (i&1)*4096];
    const u16* Vb = &lds[12288 + (i&1)*4096];

    f32x4 sT[4] = {};
    __builtin_amdgcn_s_setprio(1);
#pragma unroll
    for (int kh = 0; kh < 2; ++kh) {
      bf16x8 kf[4];
#pragma unroll
      for (int nf = 0; nf < 4; ++nf) {
        int row = nf*16 + c;
        int ch = (kh*4 + g) ^ (c & 7);
        kf[nf] = *(const bf16x8*)&Kb[row*64 + ch*8];
      }
#pragma unroll
      for (int nf = 0; nf < 4; ++nf)
        sT[nf] = __builtin_amdgcn_mfma_f32_16x16x32_bf16(kf[nf], qf[kh], sT[nf], 0,0,0);
    }
    __builtin_amdgcn_s_setprio(0);

    if (maskLast && i == nkv - 1) {
#pragma unroll
      for (int nf = 0; nf < 4; ++nf)
#pragma unroll
        for (int r = 0; r < 4; ++r)
          if (nf*16 + g*4 + r > wid*16 + c) sT[nf][r] = -INFINITY;
    }

    float mx = fmaxf(fmaxf(sT[0][0], sT[0][1]), fmaxf(sT[0][2], sT[0][3]));
#pragma unroll
    for (int nf = 1; nf < 4; ++nf)
      mx = fmaxf(mx, fmaxf(fmaxf(sT[nf][0], sT[nf][1]), fmaxf(sT[nf][2], sT[nf][3])));
    if (!__all(mx * SC <= mi + 8.f)) {
      float mxr = fmaxf(mx, __shfl_xor(mx, 16, 64));
      mxr = fmaxf(mxr, __shfl_xor(mxr, 32, 64));
      float mn = fmaxf(mi, mxr * SC);
      float corr = fexp2(mi - mn);
      li *= corr;
#pragma unroll
      for (int df = 0; df < 4; ++df) {
        o[df][0] *= corr; o[df][1] *= corr;
        o[df][2] *= corr; o[df][3] *= corr;
      }
      mi = mn;
    }
    float sum = 0.f;
#pragma unroll
    for (int nf = 0; nf < 4; ++nf)
#pragma unroll
      for (int r = 0; r < 4; ++r) {
        float pv = fexp2(fmaf(sT[nf][r], SC, -mi));
        sT[nf][r] = pv;
        sum += pv;
      }
    li += sum;

#pragma unroll
    for (int nf = 0; nf < 4; ++nf) {
      u32x2 ww;
      ww[0] = cvt_pk_bf16(sT[nf][0], sT[nf][1]);
      ww[1] = cvt_pk_bf16(sT[nf][2], sT[nf][3]);
      int ch = (2*nf + (g >> 1)) ^ cs;
      *(u32x2*)&lds[pbase + c*64 + ch*8 + (g & 1)*4] = ww;
    }
    asm volatile("s_waitcnt lgkmcnt(0)" ::: "memory");
    __builtin_amdgcn_sched_barrier(0);

    __builtin_amdgcn_s_setprio(1);
#pragma unroll
    for (int kh = 0; kh < 2; ++kh) {
      bf16x8 pfr, vf[4];
      {
        int ch = (kh*4 + g) ^ cs;
        pfr = *(const bf16x8*)&lds[pbase + c*64 + ch*8];
      }
#pragma unroll
      for (int df = 0; df < 4; ++df) {
        int d = df*16 + c;
        int ch = (kh*4 + g) ^ (d & 7);
        vf[df] = *(const bf16x8*)&Vb[d*64 + ch*8];
      }
#pragma unroll
      for (int df = 0; df < 4; ++df)
        o[df] = __builtin_amdgcn_mfma_f32_16x16x32_bf16(vf[df], pfr, o[df], 0,0,0);
    }
    __builtin_amdgcn_s_setprio(0);

    asm volatile("s_waitcnt vmcnt(0)" ::: "memory");
    __builtin_amdgcn_s_barrier();
    __builtin_amdgcn_sched_barrier(0);
  }
  MI = mi; LI = li;
}

// partial layout (u16 units, stride 4608): [0,4096) o bf16 [64][64];
// [4096,4224) m f32[64]; [4224,4352) l f32[64]; [4352,4608) pad.
__device__ __forceinline__ void store_partial(
    u16* __restrict__ part, int slot, int s,
    int wid, int g, int c, float mi, float li_tot, const f32x4 (&o)[4])
{
  u16* po = part + (size_t)(slot*2 + s) * 4608;
  int q = wid*16 + c;
#pragma unroll
  for (int df = 0; df < 4; ++df) {
    u16x4 pk;
    pk[0] = f2bf(o[df][0]); pk[1] = f2bf(o[df][1]);
    pk[2] = f2bf(o[df][2]); pk[3] = f2bf(o[df][3]);
    *(u16x4*)&po[q*64 + df*16 + g*4] = pk;
  }
  if (g == 0) {
    ((float*)(po + 4096))[q] = mi;
    ((float*)(po + 4224))[q] = li_tot;
  }
}

__global__ __launch_bounds__(256, 4) void attn_fwd(
    const u16* __restrict__ QK, const u16* __restrict__ VT,
    u16* __restrict__ AO, u16* __restrict__ part)
{
  __shared__ __align__(16) u16 lds[20480];
  const int t = threadIdx.x;
  const int wid = t >> 6, l = t & 63;
  const int g = l >> 4, c = l & 15;
  const int u = blockIdx.x;
  const int lid = (u & 7) * 128 + (u >> 3);
  const int gx = lid & 31, h = (lid >> 5) & 15, b = lid >> 9;
  const int p = gx >> 1, s = gx & 1;
  const u16* Qg  = QK + (size_t)b * 2048 * 2048 + (size_t)h * 64;
  const u16* Kg  = Qg + 1024;
  const u16* VTg = VT + (size_t)(((b << 4) + h) << 6) * 2048;
  const int arow = t >> 3, achk = t & 7;
  const int pbase = wid * 1024;
  const int cs = (c & 7) ^ ((c >> 3) << 2);
  const u16* Ka = Kg  + (size_t)arow*2048 + ((achk ^ (arow & 7)) << 3);
  const u16* Va = VTg + (size_t)arow*2048 + ((achk ^ (arow & 7)) << 3);
  const int slot = ((b*16 + h)*16 + p);

  float mi, li; f32x4 o[4];

  if (s == 0) {
    attn_phase(lds, Qg, Ka, Va, p*64, 0, p+1, true,
               wid, g, c, arow, achk, pbase, cs, mi, li, o);
    {
      float lt = li + __shfl_xor(li, 16, 64);
      lt += __shfl_xor(lt, 32, 64);
      float nr = 1.f / lt;
      int row = p*64 + wid*16 + c;
      size_t rb = ((size_t)b*2048 + row)*1024 + h*64;
#pragma unroll
      for (int df = 0; df < 4; ++df) {
        u16x4 pk;
        pk[0] = f2bf(o[df][0] * nr); pk[1] = f2bf(o[df][1] * nr);
        pk[2] = f2bf(o[df][2] * nr); pk[3] = f2bf(o[df][3] * nr);
        *(u16x4*)&AO[rb + df*16 + g*4] = pk;
      }
    }
    attn_phase(lds, Qg, Ka, Va, (31-p)*64, 0, 16-p, false,
               wid, g, c, arow, achk, pbase, cs, mi, li, o);
    float lt = li + __shfl_xor(li, 16, 64);
    lt += __shfl_xor(lt, 32, 64);
    store_partial(part, slot, 0, wid, g, c, mi, lt, o);
  } else {
    attn_phase(lds, Qg, Ka, Va, (31-p)*64, 16-p, 16, true,
               wid, g, c, arow, achk, pbase, cs, mi, li, o);
    float lt = li + __shfl_xor(li, 16, 64);
    lt += __shfl_xor(lt, 32, 64);
    store_partial(part, slot, 1, wid, g, c, mi, lt, o);
  }
}

// ---------------- merge the two partials of q-tiles 16..31 (bf16 partials) -------------
__global__ __launch_bounds__(256) void attn_merge(
    const u16* __restrict__ part, u16* __restrict__ AO)
{
  int slot = blockIdx.x;
  int p = slot & 15;
  int h = (slot >> 4) & 15;
  int b = slot >> 8;
  const u16* p0 = part + (size_t)slot * 9216;
  const u16* p1 = p0 + 4608;
  int t = threadIdx.x;
  int r = t >> 2, c0 = (t & 3) * 16;
  float m0 = ((const float*)(p0 + 4096))[r], m1 = ((const float*)(p1 + 4096))[r];
  float l0 = ((const float*)(p0 + 4224))[r], l1 = ((const float*)(p1 + 4224))[r];
  float m = fmaxf(m0, m1);
  float e0 = exp2f(m0 - m), e1 = exp2f(m1 - m);
  float rl = 1.f / (l0*e0 + l1*e1);
  e0 *= rl; e1 *= rl;
  const u16x8* a0 = (const u16x8*)(p0 + r*64 + c0);
  const u16x8* a1 = (const u16x8*)(p1 + r*64 + c0);
  int qrow = (31 - p)*64 + r;
  size_t ab = ((size_t)b*2048 + qrow)*1024 + h*64 + c0;
#pragma unroll
  for (int half = 0; half < 2; ++half) {
    u16x8 x = a0[half], y = a1[half];
    u16x8 w;
#pragma unroll
    for (int j = 0; j < 8; ++j)
      w[j] = f2bf(bf2f(x[j])*e0 + bf2f(y[j])*e1);
    *(u16x8*)&AO[ab + half*8] = w;
  }
}

// ---------------------------------------------------------------------------------------
extern "C" void kernel_launch(void* const* d_in, const int* in_sizes, int n_in,
                              void* d_out, int out_size, void* d_ws, size_t ws_size,
                              hipStream_t stream)
{
  const float* q  = (const float*)d_in[0];
  const float* k  = (const float*)d_in[1];
  const float* v  = (const float*)d_in[2];
  // d_in[3] = mask (causal tril; applied analytically)
  const float* Wq = (const float*)d_in[4];
  const float* bq = (const float*)d_in[5];
  const float* Wk = (const float*)d_in[6];
  const float* bk = (const float*)d_in[7];
  const float* Wv = (const float*)d_in[8];
  const float* bv = (const float*)d_in[9];
  const float* Wo = (const float*)d_in[10];
  const float* bo = (const float*)d_in[11];
  float* out = (float*)d_out;

  u16* ws   = (u16*)d_ws;
  // [0 .. 12.6M): attn partial buffer (bf16 o + f32 m/l)
  u16* Wqb  = ws + 12582912;      // [3][1024][1024] bf16 weights (Wq,Wk,Wv)
  u16* Wob  = ws + 15728640;      // [1024][1024]
  u16* QKp  = ws + 16777216;      // [4096][2048]  (Q | K)
  u16* VTp  = ws + 25165824;      // [2][16][64][2048]  V transposed
  u16* AO   = ws + 29360128;      // [4096][1024]

  convert_w<<<2048, 256, 0, stream>>>(Wq, Wk, Wv, Wo, Wqb);

  gemm_qkv<<<768, 256, 0, stream>>>(q, k, v, Wqb, bq, bk, bv, QKp, VTp);

  attn_fwd<<<1024, 256, 0, stream>>>(QKp, VTp, AO, ws);

  attn_merge<<<512, 256, 0, stream>>>(ws, AO);

  gemm_out<<<256, 256, 0, stream>>>(AO, Wob, bo, out);
}

// Round 18
// 100.432 us; speedup vs baseline: 1.3756x; 1.0088x over previous
//
#include <hip/hip_runtime.h>

typedef unsigned int u32;
typedef unsigned short u16;
typedef __attribute__((ext_vector_type(8))) short bf16x8;
typedef __attribute__((ext_vector_type(8))) u16 u16x8;
typedef __attribute__((ext_vector_type(4))) u16 u16x4;
typedef __attribute__((ext_vector_type(4))) float f32x4;
typedef __attribute__((ext_vector_type(2))) u32 u32x2;

#define AS1 __attribute__((address_space(1)))
#define AS3 __attribute__((address_space(3)))

__device__ __forceinline__ void gload_lds16(const void* g, void* l) {
  __builtin_amdgcn_global_load_lds((const AS1 u32*)g, (AS3 u32*)l, 16, 0, 0);
}

__device__ __forceinline__ u16 f2bf(float f) {
  union { float f; u32 u; } x; x.f = f;
  u32 u = x.u;
  return (u16)((u + 0x7fffu + ((u >> 16) & 1u)) >> 16);
}

__device__ __forceinline__ float bf2f(u16 v) {
  union { u32 u; float f; } x; x.u = (u32)v << 16; return x.f;
}

__device__ __forceinline__ u32 cvt_pk_bf16(float lo, float hi) {
  u32 r;
  asm("v_cvt_pk_bf16_f32 %0, %1, %2" : "=v"(r) : "v"(lo), "v"(hi));
  return r;
}

__device__ __forceinline__ float fexp2(float x) {
  float r;
  asm("v_exp_f32 %0, %1" : "=v"(r) : "v"(x));
  return r;
}

// ---------------- convert fp32 -> bf16, WEIGHTS ONLY (Wq,Wk,Wv,Wo) ---------------------
__global__ __launch_bounds__(256) void convert_w(
    const float* __restrict__ wq, const float* __restrict__ wk,
    const float* __restrict__ wv, const float* __restrict__ wo,
    u16* __restrict__ dst)
{
  int b = blockIdx.x, t = threadIdx.x;
  int w = b >> 9;
  const float* sp = (w == 0) ? wq : ((w == 1) ? wk : ((w == 2) ? wv : wo));
  size_t lb = (size_t)(b & 511) * 2048 + (size_t)t * 8;
  f32x4 f0 = *(const f32x4*)(sp + lb);
  f32x4 f1 = *(const f32x4*)(sp + lb + 4);
  u16x8 o;
  o[0]=f2bf(f0[0]); o[1]=f2bf(f0[1]); o[2]=f2bf(f0[2]); o[3]=f2bf(f0[3]);
  o[4]=f2bf(f1[0]); o[5]=f2bf(f1[1]); o[6]=f2bf(f1[2]); o[7]=f2bf(f1[3]);
  *(u16x8*)(dst + (size_t)b*2048 + (size_t)t*8) = o;
}

// ---------------- fused QKV GEMM, 128x128, BK=32, ring-3, fp32-A fused convert ---------
// (r11/r17 version, frozen)
__global__ __launch_bounds__(256, 3) void gemm_qkv(
    const float* __restrict__ Xq, const float* __restrict__ Xk, const float* __restrict__ Xv,
    const u16* __restrict__ Wall,
    const float* __restrict__ bq, const float* __restrict__ bk, const float* __restrict__ bv,
    u16* __restrict__ Cqk, u16* __restrict__ VT)
{
  __shared__ __align__(16) u16 lds[24576];
  const int t = threadIdx.x;
  const int wid = t >> 6, l = t & 63;
  const int c = l & 15, g = l >> 4;
  const int u = blockIdx.x;
  const int lid = (u & 7) * 96 + (u >> 3);
  const int which = lid >> 8;
  const int r5 = lid & 255;
  const int m0 = (r5 >> 3) * 128, n0 = (r5 & 7) * 128;
  const float* Afp = (which == 0) ? Xq : ((which == 1) ? Xk : Xv);
  const u16* Bw = Wall + (size_t)which * 1048576;
  const int wr = wid >> 1, wc = wid & 1;

  const int srow = wid*16 + (l >> 2);
  const int gch = ((l & 3) ^ (srow & 3) ^ ((srow >> 2) & 3)) << 3;
  const float* Ag0 = Afp + (size_t)(m0 + srow)*1024      + gch;
  const float* Ag1 = Afp + (size_t)(m0 + 64 + srow)*1024 + gch;
  const int awr0 = wid*512 + l*8;
  const int awr1 = 2048 + wid*512 + l*8;
  const u16* Bsrc0 = Bw + (size_t)(n0 + srow)*1024      + gch;
  const u16* Bsrc1 = Bw + (size_t)(n0 + 64 + srow)*1024 + gch;
  const int wbase = wid * 512;

  f32x4 ra0, ra1, ra2, ra3;

#define A_LOAD(j) do { \
    const float* ap0_ = Ag0 + ((j) << 5); \
    const float* ap1_ = Ag1 + ((j) << 5); \
    ra0 = *(const f32x4*)ap0_; ra1 = *(const f32x4*)(ap0_ + 4); \
    ra2 = *(const f32x4*)ap1_; ra3 = *(const f32x4*)(ap1_ + 4); \
  } while (0)

#define A_CVT_WRITE(j) do { \
    const int bo_ = ((j) % 3) * 8192; \
    u16x8 w0_, w1_; u32* q0_ = (u32*)&w0_; u32* q1_ = (u32*)&w1_; \
    q0_[0]=cvt_pk_bf16(ra0[0],ra0[1]); q0_[1]=cvt_pk_bf16(ra0[2],ra0[3]); \
    q0_[2]=cvt_pk_bf16(ra1[0],ra1[1]); q0_[3]=cvt_pk_bf16(ra1[2],ra1[3]); \
    q1_[0]=cvt_pk_bf16(ra2[0],ra2[1]); q1_[1]=cvt_pk_bf16(ra2[2],ra2[3]); \
    q1_[2]=cvt_pk_bf16(ra3[0],ra3[1]); q1_[3]=cvt_pk_bf16(ra3[2],ra3[3]); \
    *(u16x8*)&lds[bo_ + awr0] = w0_; \
    *(u16x8*)&lds[bo_ + awr1] = w1_; \
  } while (0)

#define B_STAGE(j) do { \
    const int bo_ = ((j) % 3) * 8192; const int ko_ = (j) << 5; \
    gload_lds16(Bsrc0 + ko_, &lds[bo_ + 4096 + wbase]); \
    gload_lds16(Bsrc1 + ko_, &lds[bo_ + 6144 + wbase]); \
  } while (0)

  const int fswz = (g ^ (c & 3) ^ ((c >> 2) & 3)) << 3;
  const int abase = (wr*64 + c)*32 + fswz;
  const int bbase = 4096 + (wc*64 + c)*32 + fswz;

  f32x4 acc[4][4] = {};

  A_LOAD(0);
  B_STAGE(0);
  B_STAGE(1);
  asm volatile("s_waitcnt vmcnt(2)" ::: "memory");
  A_CVT_WRITE(0);
  A_LOAD(1);
  asm volatile("s_waitcnt lgkmcnt(0)" ::: "memory");
  __builtin_amdgcn_s_barrier();
  __builtin_amdgcn_sched_barrier(0);

#pragma unroll
  for (int tstep = 0; tstep < 32; ++tstep) {
    if (tstep + 2 < 32) B_STAGE(tstep + 2);
    const int bo = (tstep % 3) * 8192;
    bf16x8 af[4], bf[4];
#pragma unroll
    for (int mf = 0; mf < 4; ++mf)
      af[mf] = *(const bf16x8*)&lds[bo + abase + mf*512];
#pragma unroll
    for (int nf = 0; nf < 4; ++nf)
      bf[nf] = *(const bf16x8*)&lds[bo + bbase + nf*512];
    __builtin_amdgcn_s_setprio(1);
#pragma unroll
    for (int mf = 0; mf < 4; ++mf)
#pragma unroll
      for (int nf = 0; nf < 4; ++nf)
        acc[mf][nf] = __builtin_amdgcn_mfma_f32_16x16x32_bf16(af[mf], bf[nf], acc[mf][nf], 0, 0, 0);
    __builtin_amdgcn_s_setprio(0);
    if (tstep + 1 < 32) {
      if (tstep + 2 < 32) asm volatile("s_waitcnt vmcnt(2)" ::: "memory");
      else                asm volatile("s_waitcnt vmcnt(0)" ::: "memory");
      A_CVT_WRITE(tstep + 1);
      if (tstep + 2 < 32) A_LOAD(tstep + 2);
    }
    asm volatile("s_waitcnt lgkmcnt(0)" ::: "memory");
    __builtin_amdgcn_s_barrier();
    __builtin_amdgcn_sched_barrier(0);
  }
#undef A_LOAD
#undef A_CVT_WRITE
#undef B_STAGE

  const float* bias = (which == 0) ? bq : ((which == 1) ? bk : bv);
  if (which < 2) {
#pragma unroll
    for (int mf = 0; mf < 4; ++mf)
#pragma unroll
      for (int nf = 0; nf < 4; ++nf) {
        int row = m0 + wr*64 + mf*16 + g*4;
        int col = n0 + wc*64 + nf*16 + c;
        float bv_ = bias[col];
        int colg = which*1024 + col;
#pragma unroll
        for (int r = 0; r < 4; ++r)
          Cqk[(size_t)(row+r)*2048 + colg] = f2bf(acc[mf][nf][r] + bv_);
      }
  } else {
#pragma unroll
    for (int mf = 0; mf < 4; ++mf)
#pragma unroll
      for (int nf = 0; nf < 4; ++nf) {
        int row = m0 + wr*64 + mf*16 + g*4;
        int col = n0 + wc*64 + nf*16 + c;
        float bv_ = bias[col];
        int bb2 = row >> 11, s = row & 2047;
        int hh = col >> 6, dh = col & 63;
        u16x4 pk;
#pragma unroll
        for (int r = 0; r < 4; ++r) pk[r] = f2bf(acc[mf][nf][r] + bv_);
        *(u16x4*)&VT[((size_t)(((bb2<<4)+hh)<<6) + dh)*2048 + s] = pk;
      }
  }
}

// ---------------- GEMM out = AO * Wo^T + bo, 128x128, BK=32, ring-3, fp32 out ----------
// (r11/r17 version, frozen)
__global__ __launch_bounds__(256, 3) void gemm_out(
    const u16* __restrict__ A, const u16* __restrict__ Bw,
    const float* __restrict__ bias, float* __restrict__ C)
{
  __shared__ __align__(16) u16 lds[24576];
  const int t = threadIdx.x;
  const int wid = t >> 6, l = t & 63;
  const int c = l & 15, g = l >> 4;
  const int u = blockIdx.x;
  const int lid = (u & 7) * 32 + (u >> 3);
  const int m0 = (lid >> 3) * 128, n0 = (lid & 7) * 128;
  const int wr = wid >> 1, wc = wid & 1;

  const int srow = wid*16 + (l >> 2);
  const int sswz = (((l & 3) ^ (srow & 3) ^ ((srow >> 2) & 3)) << 3);
  const u16* Asrc0 = A  + (size_t)(m0 + srow)*1024      + sswz;
  const u16* Asrc1 = A  + (size_t)(m0 + 64 + srow)*1024 + sswz;
  const u16* Bsrc0 = Bw + (size_t)(n0 + srow)*1024      + sswz;
  const u16* Bsrc1 = Bw + (size_t)(n0 + 64 + srow)*1024 + sswz;
  const int wbase = wid * 512;

#define O_STAGE(j) do { \
    const int bo_ = ((j) % 3) * 8192; const int ko_ = (j) << 5; \
    gload_lds16(Asrc0 + ko_, &lds[bo_ + wbase]); \
    gload_lds16(Asrc1 + ko_, &lds[bo_ + 2048 + wbase]); \
    gload_lds16(Bsrc0 + ko_, &lds[bo_ + 4096 + wbase]); \
    gload_lds16(Bsrc1 + ko_, &lds[bo_ + 6144 + wbase]); \
  } while (0)

  const int fswz = (g ^ (c & 3) ^ ((c >> 2) & 3)) << 3;
  const int abase = (wr*64 + c)*32 + fswz;
  const int bbase = 4096 + (wc*64 + c)*32 + fswz;

  f32x4 acc[4][4] = {};

  O_STAGE(0);
  O_STAGE(1);
  asm volatile("s_waitcnt vmcnt(4)" ::: "memory");
  __builtin_amdgcn_s_barrier();
  __builtin_amdgcn_sched_barrier(0);

#pragma unroll
  for (int tstep = 0; tstep < 32; ++tstep) {
    if (tstep + 2 < 32) O_STAGE(tstep + 2);
    const int bo = (tstep % 3) * 8192;
    bf16x8 af[4], bf[4];
#pragma unroll
    for (int mf = 0; mf < 4; ++mf)
      af[mf] = *(const bf16x8*)&lds[bo + abase + mf*512];
#pragma unroll
    for (int nf = 0; nf < 4; ++nf)
      bf[nf] = *(const bf16x8*)&lds[bo + bbase + nf*512];
    __builtin_amdgcn_s_setprio(1);
#pragma unroll
    for (int mf = 0; mf < 4; ++mf)
#pragma unroll
      for (int nf = 0; nf < 4; ++nf)
        acc[mf][nf] = __builtin_amdgcn_mfma_f32_16x16x32_bf16(af[mf], bf[nf], acc[mf][nf], 0, 0, 0);
    __builtin_amdgcn_s_setprio(0);
    if (tstep + 2 < 32) asm volatile("s_waitcnt vmcnt(4)" ::: "memory");
    else                asm volatile("s_waitcnt vmcnt(0)" ::: "memory");
    __builtin_amdgcn_s_barrier();
    __builtin_amdgcn_sched_barrier(0);
  }
#undef O_STAGE

#pragma unroll
  for (int mf = 0; mf < 4; ++mf)
#pragma unroll
    for (int nf = 0; nf < 4; ++nf) {
      int row = m0 + wr*64 + mf*16 + g*4;
      int col = n0 + wc*64 + nf*16 + c;
      float bv_ = bias[col];
#pragma unroll
      for (int r = 0; r < 4; ++r)
        C[(size_t)(row+r)*1024 + col] = acc[mf][nf][r] + bv_;
    }
}

// ---------------- causal flash attention, QBLK=128 fat iterations, KVBLK=64 ------------
// 4 waves x 32 q-rows (2 mf frags). Split-KV pairing {p,15-p}: 17 fat iters/block
// uniform; grid 512 = 2 blocks/CU, XCD-chunked. LDS 48KB: Q/P 16K + K dbuf 16K +
// V dbuf 16K. Diagonal spans 2 KV tiles -> elementwise mask on last 2 iters.
__device__ __forceinline__ void stage_kv(u16* lds, const u16* Kt, const u16* Vt,
                                         int buf, int wid) {
#pragma unroll
  for (int ii = 0; ii < 2; ++ii)
    gload_lds16(Kt + (size_t)ii*32*2048, &lds[8192  + buf*4096 + ii*2048 + wid*512]);
#pragma unroll
  for (int ii = 0; ii < 2; ++ii)
    gload_lds16(Vt + (size_t)ii*32*2048, &lds[16384 + buf*4096 + ii*2048 + wid*512]);
}

__device__ __forceinline__ void attn_phase(
    u16* lds, const u16* Qg, const u16* Ka, const u16* Va,
    int q0, int kt0, int nkv, bool maskTail,
    int wid, int g, int c, int arow, int achk, int pbase, int cs,
    float (&mi)[2], float (&li)[2], f32x4 (&o)[2][4])
{
  const float SC = 0.18033688f;  // (1/8) * log2(e)
  // stage Q tile [128][64] swizzled
#pragma unroll
  for (int i = 0; i < 4; ++i) {
    int row = i*32 + arow;
    gload_lds16(Qg + (size_t)(q0+row)*2048 + ((achk ^ (row&7)) << 3),
                &lds[i*2048 + wid*512]);
  }
  const u16* Kt = Ka + (size_t)kt0 * (64*2048);
  const u16* Vt = Va + kt0 * 64;
  stage_kv(lds, Kt, Vt, 0, wid);
  asm volatile("s_waitcnt vmcnt(0)" ::: "memory");
  __builtin_amdgcn_s_barrier();
  __builtin_amdgcn_sched_barrier(0);

  bf16x8 qf[2][2];
#pragma unroll
  for (int mf = 0; mf < 2; ++mf)
#pragma unroll
    for (int kh = 0; kh < 2; ++kh) {
      int row = wid*32 + mf*16 + c;
      int ch = (kh*4 + g) ^ (c & 7);
      qf[mf][kh] = *(const bf16x8*)&lds[row*64 + ch*8];
    }
  __builtin_amdgcn_s_barrier();   // Q frags in regs; region may be reused for P

#pragma unroll
  for (int mf = 0; mf < 2; ++mf) {
    mi[mf] = -INFINITY; li[mf] = 0.f;
#pragma unroll
    for (int df = 0; df < 4; ++df) o[mf][df] = f32x4{0.f, 0.f, 0.f, 0.f};
  }
  const int qb0 = q0 + wid*32;

  for (int i = 0; i < nkv; ++i) {
    if (i + 1 < nkv) {
      Kt += 64*2048; Vt += 64;
      stage_kv(lds, Kt, Vt, (i+1)&1, wid);
    }
    const u16* Kb = &lds[8192  + (i&1)*4096];
    const u16* Vb = &lds[16384 + (i&1)*4096];

    // QK^T swapped: lane holds q = c (within mf frag), k = 16nf + 4g + r
    f32x4 sT[2][4] = {};
    __builtin_amdgcn_s_setprio(1);
#pragma unroll
    for (int kh = 0; kh < 2; ++kh) {
      bf16x8 kf[4];
#pragma unroll
      for (int nf = 0; nf < 4; ++nf) {
        int row = nf*16 + c;
        int ch = (kh*4 + g) ^ (c & 7);
        kf[nf] = *(const bf16x8*)&Kb[row*64 + ch*8];
      }
#pragma unroll
      for (int mf = 0; mf < 2; ++mf)
#pragma unroll
        for (int nf = 0; nf < 4; ++nf)
          sT[mf][nf] = __builtin_amdgcn_mfma_f32_16x16x32_bf16(kf[nf], qf[mf][kh], sT[mf][nf], 0,0,0);
    }
    __builtin_amdgcn_s_setprio(0);

    if (maskTail && i >= nkv - 2) {   // diagonal (2 KV tiles), elementwise mask
      const int k0g = (kt0 + i) * 64;
#pragma unroll
      for (int mf = 0; mf < 2; ++mf)
#pragma unroll
        for (int nf = 0; nf < 4; ++nf)
#pragma unroll
          for (int r = 0; r < 4; ++r)
            if (k0g + nf*16 + g*4 + r > qb0 + mf*16 + c) sT[mf][nf][r] = -INFINITY;
    }

    // defer-max online softmax, per mf frag (independent q-rows)
#pragma unroll
    for (int mf = 0; mf < 2; ++mf) {
      float mx = fmaxf(fmaxf(sT[mf][0][0], sT[mf][0][1]), fmaxf(sT[mf][0][2], sT[mf][0][3]));
#pragma unroll
      for (int nf = 1; nf < 4; ++nf)
        mx = fmaxf(mx, fmaxf(fmaxf(sT[mf][nf][0], sT[mf][nf][1]), fmaxf(sT[mf][nf][2], sT[mf][nf][3])));
      if (!__all(mx * SC <= mi[mf] + 8.f)) {
        float mxr = fmaxf(mx, __shfl_xor(mx, 16, 64));
        mxr = fmaxf(mxr, __shfl_xor(mxr, 32, 64));
        float mn = fmaxf(mi[mf], mxr * SC);
        float corr = fexp2(mi[mf] - mn);
        li[mf] *= corr;
#pragma unroll
        for (int df = 0; df < 4; ++df) {
          o[mf][df][0] *= corr; o[mf][df][1] *= corr;
          o[mf][df][2] *= corr; o[mf][df][3] *= corr;
        }
        mi[mf] = mn;
      }
      float sum = 0.f;
#pragma unroll
      for (int nf = 0; nf < 4; ++nf)
#pragma unroll
        for (int r = 0; r < 4; ++r) {
          float pv = fexp2(fmaf(sT[mf][nf][r], SC, -mi[mf]));
          sT[mf][nf][r] = pv;
          sum += pv;
        }
      li[mf] += sum;

      // P -> LDS (wave-private, per-mf 1KB sub-region)
#pragma unroll
      for (int nf = 0; nf < 4; ++nf) {
        u32x2 ww;
        ww[0] = cvt_pk_bf16(sT[mf][nf][0], sT[mf][nf][1]);
        ww[1] = cvt_pk_bf16(sT[mf][nf][2], sT[mf][nf][3]);
        int ch = (2*nf + (g >> 1)) ^ cs;
        *(u32x2*)&lds[pbase + mf*1024 + c*64 + ch*8 + (g & 1)*4] = ww;
      }
    }
    asm volatile("s_waitcnt lgkmcnt(0)" ::: "memory");
    __builtin_amdgcn_sched_barrier(0);

    // PV swapped: o[mf][df] = V^T-frag x P[mf]-frag
    __builtin_amdgcn_s_setprio(1);
#pragma unroll
    for (int kh = 0; kh < 2; ++kh) {
      bf16x8 pfr[2], vf[4];
#pragma unroll
      for (int mf = 0; mf < 2; ++mf) {
        int ch = (kh*4 + g) ^ cs;
        pfr[mf] = *(const bf16x8*)&lds[pbase + mf*1024 + c*64 + ch*8];
      }
#pragma unroll
      for (int df = 0; df < 4; ++df) {
        int d = df*16 + c;
        int ch = (kh*4 + g) ^ (d & 7);
        vf[df] = *(const bf16x8*)&Vb[d*64 + ch*8];
      }
#pragma unroll
      for (int mf = 0; mf < 2; ++mf)
#pragma unroll
        for (int df = 0; df < 4; ++df)
          o[mf][df] = __builtin_amdgcn_mfma_f32_16x16x32_bf16(vf[df], pfr[mf], o[mf][df], 0,0,0);
    }
    __builtin_amdgcn_s_setprio(0);

    asm volatile("s_waitcnt vmcnt(0)" ::: "memory");  // next K/V tile landed
    __builtin_amdgcn_s_barrier();
    __builtin_amdgcn_sched_barrier(0);
  }
}

// partial layout (u16 units, stride 8704): [0,8192) o bf16 [128][64];
// [8192,8448) m f32[128]; [8448,8704) l f32[128].
__device__ __forceinline__ void store_partial(
    u16* __restrict__ part, int slot, int s,
    int wid, int g, int c, const float (&mi)[2], const float (&lt)[2],
    const f32x4 (&o)[2][4])
{
  u16* po = part + (size_t)(slot*2 + s) * 8704;
#pragma unroll
  for (int mf = 0; mf < 2; ++mf) {
    int q = wid*32 + mf*16 + c;
#pragma unroll
    for (int df = 0; df < 4; ++df) {
      u16x4 pk;
      pk[0] = f2bf(o[mf][df][0]); pk[1] = f2bf(o[mf][df][1]);
      pk[2] = f2bf(o[mf][df][2]); pk[3] = f2bf(o[mf][df][3]);
      *(u16x4*)&po[q*64 + df*16 + g*4] = pk;
    }
    if (g == 0) {
      ((float*)(po + 8192))[q] = mi[mf];
      ((float*)(po + 8448))[q] = lt[mf];
    }
  }
}

__global__ __launch_bounds__(256, 2) void attn_fwd(
    const u16* __restrict__ QK, const u16* __restrict__ VT,
    u16* __restrict__ AO, u16* __restrict__ part)
{
  // u16 units: [0,8192) Q staging / per-wave P (wave w: w*2048);
  // [8192,16384) K dbuf; [16384,24576) V dbuf. 48 KB.
  __shared__ __align__(16) u16 lds[24576];
  const int t = threadIdx.x;
  const int wid = t >> 6, l = t & 63;
  const int g = l >> 4, c = l & 15;
  const int u = blockIdx.x;
  const int lid = (u & 7) * 64 + (u >> 3);       // 512 % 8 == 0, bijective
  const int gx = lid & 15, h = (lid >> 4) & 15, b = lid >> 8;
  const int p = gx >> 1, s = gx & 1;             // pair {p, 15-p}, p in [0,8)
  const u16* Qg  = QK + (size_t)b * 2048 * 2048 + (size_t)h * 64;
  const u16* Kg  = Qg + 1024;
  const u16* VTg = VT + (size_t)(((b << 4) + h) << 6) * 2048;
  const int arow = t >> 3, achk = t & 7;
  const int pbase = wid * 2048;
  const int cs = (c & 7) ^ ((c >> 3) << 2);
  const u16* Ka = Kg  + (size_t)arow*2048 + ((achk ^ (arow & 7)) << 3);
  const u16* Va = VTg + (size_t)arow*2048 + ((achk ^ (arow & 7)) << 3);
  const int slot = ((b*16 + h)*8 + p);

  float mi[2], li[2]; f32x4 o[2][4];

  if (s == 0) {
    // phase A: q-tile p (rows 128p..), KV 0..2p+1, final output
    attn_phase(lds, Qg, Ka, Va, p*128, 0, 2*p+2, true,
               wid, g, c, arow, achk, pbase, cs, mi, li, o);
#pragma unroll
    for (int mf = 0; mf < 2; ++mf) {
      float lt = li[mf] + __shfl_xor(li[mf], 16, 64);
      lt += __shfl_xor(lt, 32, 64);
      float nr = 1.f / lt;
      int row = p*128 + wid*32 + mf*16 + c;
      size_t rb = ((size_t)b*2048 + row)*1024 + h*64;
#pragma unroll
      for (int df = 0; df < 4; ++df) {
        u16x4 pk;
        pk[0] = f2bf(o[mf][df][0] * nr); pk[1] = f2bf(o[mf][df][1] * nr);
        pk[2] = f2bf(o[mf][df][2] * nr); pk[3] = f2bf(o[mf][df][3] * nr);
        *(u16x4*)&AO[rb + df*16 + g*4] = pk;
      }
    }
    __builtin_amdgcn_s_barrier();
    // phase B: q-tile 15-p, KV 0..14-2p (partial, no mask)
    attn_phase(lds, Qg, Ka, Va, (15-p)*128, 0, 15-2*p, false,
               wid, g, c, arow, achk, pbase, cs, mi, li, o);
    float lt[2];
#pragma unroll
    for (int mf = 0; mf < 2; ++mf) {
      lt[mf] = li[mf] + __shfl_xor(li[mf], 16, 64);
      lt[mf] += __shfl_xor(lt[mf], 32, 64);
    }
    store_partial(part, slot, 0, wid, g, c, mi, lt, o);
  } else {
    // q-tile 15-p, KV 15-2p..31-2p (17 tiles incl. 2-tile diagonal)
    attn_phase(lds, Qg, Ka, Va, (15-p)*128, 15-2*p, 17, true,
               wid, g, c, arow, achk, pbase, cs, mi, li, o);
    float lt[2];
#pragma unroll
    for (int mf = 0; mf < 2; ++mf) {
      lt[mf] = li[mf] + __shfl_xor(li[mf], 16, 64);
      lt[mf] += __shfl_xor(lt[mf], 32, 64);
    }
    store_partial(part, slot, 1, wid, g, c, mi, lt, o);
  }
}

// ---------------- merge the two partials of q-tiles 8..15 (128-row, bf16) --------------
__global__ __launch_bounds__(256) void attn_merge(
    const u16* __restrict__ part, u16* __restrict__ AO)
{
  int slot = blockIdx.x;            // ((b*16+h)*8 + p), 256 total
  int p = slot & 7;
  int h = (slot >> 3) & 15;
  int b = slot >> 7;
  const u16* p0 = part + (size_t)slot * 17408;
  const u16* p1 = p0 + 8704;
  int t = threadIdx.x;
  int r = t >> 1, c0 = (t & 1) * 32;
  float m0 = ((const float*)(p0 + 8192))[r], m1 = ((const float*)(p1 + 8192))[r];
  float l0 = ((const float*)(p0 + 8448))[r], l1 = ((const float*)(p1 + 8448))[r];
  float m = fmaxf(m0, m1);
  float e0 = exp2f(m0 - m), e1 = exp2f(m1 - m);
  float rl = 1.f / (l0*e0 + l1*e1);
  e0 *= rl; e1 *= rl;
  const u16x8* a0 = (const u16x8*)(p0 + r*64 + c0);
  const u16x8* a1 = (const u16x8*)(p1 + r*64 + c0);
  int qrow = (15 - p)*128 + r;
  size_t ab = ((size_t)b*2048 + qrow)*1024 + h*64 + c0;
#pragma unroll
  for (int q8 = 0; q8 < 4; ++q8) {
    u16x8 x = a0[q8], y = a1[q8];
    u16x8 w;
#pragma unroll
    for (int j = 0; j < 8; ++j)
      w[j] = f2bf(bf2f(x[j])*e0 + bf2f(y[j])*e1);
    *(u16x8*)&AO[ab + q8*8] = w;
  }
}

// ---------------------------------------------------------------------------------------
extern "C" void kernel_launch(void* const* d_in, const int* in_sizes, int n_in,
                              void* d_out, int out_size, void* d_ws, size_t ws_size,
                              hipStream_t stream)
{
  const float* q  = (const float*)d_in[0];
  const float* k  = (const float*)d_in[1];
  const float* v  = (const float*)d_in[2];
  // d_in[3] = mask (causal tril; applied analytically)
  const float* Wq = (const float*)d_in[4];
  const float* bq = (const float*)d_in[5];
  const float* Wk = (const float*)d_in[6];
  const float* bk = (const float*)d_in[7];
  const float* Wv = (const float*)d_in[8];
  const float* bv = (const float*)d_in[9];
  const float* Wo = (const float*)d_in[10];
  const float* bo = (const float*)d_in[11];
  float* out = (float*)d_out;

  u16* ws   = (u16*)d_ws;
  // [0 .. 12.6M): attn partial buffer (bf16 o + f32 m/l; 256 slots x 2 x 8704 u16)
  u16* Wqb  = ws + 12582912;      // [3][1024][1024] bf16 weights (Wq,Wk,Wv)
  u16* Wob  = ws + 15728640;      // [1024][1024]
  u16* QKp  = ws + 16777216;      // [4096][2048]  (Q | K)
  u16* VTp  = ws + 25165824;      // [2][16][64][2048]  V transposed
  u16* AO   = ws + 29360128;      // [4096][1024]

  convert_w<<<2048, 256, 0, stream>>>(Wq, Wk, Wv, Wo, Wqb);

  gemm_qkv<<<768, 256, 0, stream>>>(q, k, v, Wqb, bq, bk, bv, QKp, VTp);

  attn_fwd<<<512, 256, 0, stream>>>(QKp, VTp, AO, ws);

  attn_merge<<<256, 256, 0, stream>>>(ws, AO);

  gemm_out<<<256, 256, 0, stream>>>(AO, Wob, bo, out);
}